// Round 11
// baseline (95.818 us; speedup 1.0000x reference)
//
#include <hip/hip_runtime.h>
#include <math.h>

#define BB 64          // batch
#define CC 16          // children per sample
#define DD 512         // feature dim
#define LL 8192        // CC*DD flattened length
#define EPSV 1e-8f
#define INVT 10.0f     // 1/TEMPERATURE

// ws layout (floats):
//  [0,1024)    esum : per-(anchor, jt) partial sum of exp(logit) over the
//                     4 j's x 2 sides handled by sim block (i,jt)
//  [1024,1088) l0   : positive logit per anchor (already /T)
#define WS_ESUM 0
#define WS_L0   1024

__device__ __forceinline__ float dot4(float4 a, float4 b) {
    return a.x * b.x + a.y * b.y + a.z * b.z + a.w * b.w;
}

__device__ __forceinline__ float wave_reduce(float v) {
    #pragma unroll
    for (int off = 32; off; off >>= 1) v += __shfl_down(v, off);
    return v;
}

// ---------------------------------------------------------------------------
// main — r7 with the previously-confounded experiment run clean:
//   FLAT it*jj gather loop + ALL reduces deferred to one tail phase,
//   WITH __launch_bounds__(256,2) (VGPR cap 128).
// Rationale: __shfl is ds_bpermute on CDNA and shares lgkmcnt with the
// ds_read of the next phase's sidx indices, so in the phased source every
// jj ends in a lgkmcnt(0) reduce wall the compiler cannot hoist loads past
// (r10 proved more VGPRs alone change nothing). The flat loop removes the
// walls at source level; cap 128 funds fiv(32) + 16 accumulators + ~15
// in-flight float4 dests. r3's version of this spilled ONLY because
// launch_bounds(256,4) capped VGPR at 64 (114MB scratch writes observed);
// r2's version was poisoned by readfirstlane-on-global (per-index vmcnt).
//   blocks [0,1024): sim role (jt=b&15, i=b>>4, 4 j's per block). Row norms
//     and anchor norm accumulate as dot4(v,v) on register-resident data;
//     epilogue finishes logits to exp() locally (|logit|<=10 -> no max pass)
//     and writes ONE esum partial per block.
//   blocks [1024,1088): pos role, anchor i=b-1024: l0 = cos(fi,fj)/T.
// ---------------------------------------------------------------------------
__global__ __launch_bounds__(256, 2) void ntx_main(const float* __restrict__ ci,
                                                   const float* __restrict__ cj,
                                                   const int* __restrict__ pids,
                                                   const int* __restrict__ nj,
                                                   const int* __restrict__ nk,
                                                   float* __restrict__ ws) {
    const int b = blockIdx.x, tid = threadIdx.x;

    if (b < 1024) {
        // ---- sim role ----
        __shared__ int   sidx[2][4][16];     // [side][jj][c]
        __shared__ float red[4][4][4];       // [jj][{aj,ak,gj,gk}][wave]
        __shared__ float nred[4];            // anchor-norm partials per wave
        const int jt = b & 15;    // 0..15
        const int i  = b >> 4;    // 0..63

        if (tid < 64)        ((int*)sidx)[tid] = nj[i * 1024 + jt * 64 + tid];
        else if (tid < 128)  ((int*)sidx)[tid] = nk[i * 1024 + jt * 64 + (tid - 64)];

        const float4* fi4 = (const float4*)(ci + i * LL);
        float4 fiv[8];
        float nacc = 0.f;
        #pragma unroll
        for (int it = 0; it < 8; ++it) {
            fiv[it] = fi4[tid + 256 * it];
            nacc += dot4(fiv[it], fiv[it]);
        }

        __syncthreads();

        const int d4   = tid & 127;   // float4 offset within a child row
        const int half = tid >> 7;    // c parity handled by this half
        const int wave = tid >> 6;
        const float4* cj4 = (const float4*)cj;
        const float4* ci4 = (const float4*)ci;

        float aj[4] = {0.f, 0.f, 0.f, 0.f};
        float ak[4] = {0.f, 0.f, 0.f, 0.f};
        float gj[4] = {0.f, 0.f, 0.f, 0.f};
        float gk[4] = {0.f, 0.f, 0.f, 0.f};

        // flat gather loop: no cross-lane ops anywhere inside -> no lgkmcnt
        // reduce walls between load batches; compiler free to keep many
        // float4 loads in flight within the 128-VGPR budget.
        #pragma unroll
        for (int it = 0; it < 8; ++it) {
            const int c = half + 2 * it;           // (tid + it*256) >> 7
            #pragma unroll
            for (int jj = 0; jj < 4; ++jj) {
                const int j = jt * 4 + jj;
                float4 vj = cj4[(j * CC + sidx[0][jj][c]) * 128 + d4];
                float4 vk = ci4[(j * CC + sidx[1][jj][c]) * 128 + d4];
                aj[jj] += dot4(fiv[it], vj);
                gj[jj] += dot4(vj, vj);
                ak[jj] += dot4(fiv[it], vk);
                gk[jj] += dot4(vk, vk);
            }
        }

        // deferred reduce phase: 17 independent 6-deep shfl chains pipeline
        {
            float nr = wave_reduce(nacc);
            if ((tid & 63) == 0) nred[wave] = nr;
        }
        #pragma unroll
        for (int jj = 0; jj < 4; ++jj) {
            float raj = wave_reduce(aj[jj]);
            float rak = wave_reduce(ak[jj]);
            float rgj = wave_reduce(gj[jj]);
            float rgk = wave_reduce(gk[jj]);
            if ((tid & 63) == 0) {
                red[jj][0][wave] = raj; red[jj][1][wave] = rak;
                red[jj][2][wave] = rgj; red[jj][3][wave] = rgk;
            }
        }
        __syncthreads();
        if (tid < 4) {
            const int jj = tid, j = jt * 4 + jj;
            const float saj = red[jj][0][0] + red[jj][0][1] + red[jj][0][2] + red[jj][0][3];
            const float sak = red[jj][1][0] + red[jj][1][1] + red[jj][1][2] + red[jj][1][3];
            const float sgj = red[jj][2][0] + red[jj][2][1] + red[jj][2][2] + red[jj][2][3];
            const float sgk = red[jj][3][0] + red[jj][3][1] + red[jj][3][2] + red[jj][3][3];
            const float si = nred[0] + nred[1] + nred[2] + nred[3];
            const float ni = fmaxf(sqrtf(si), EPSV);
            float e = 0.f;
            if ((j != i) && (pids[j] != pids[i])) {
                const float inv = INVT / ni;
                const float lj = saj / fmaxf(sqrtf(sgj), EPSV) * inv;   // in [-10,10]
                const float lk = sak / fmaxf(sqrtf(sgk), EPSV) * inv;
                e = __expf(lj) + __expf(lk);                            // <= 4.5e4, safe
            }
            e += __shfl_xor(e, 1);
            e += __shfl_xor(e, 2);
            if (jj == 0) ws[WS_ESUM + i * 16 + jt] = e;
        }
    } else {
        // ---- pos role ----
        __shared__ float pr[3][4];
        const int i = b - 1024;
        const float4* fi = (const float4*)(ci + i * LL);
        const float4* fj = (const float4*)(cj + i * LL);
        float d = 0.f, a2 = 0.f, b2 = 0.f;
        #pragma unroll
        for (int it = 0; it < 8; ++it) {
            float4 u = fi[tid + 256 * it];
            float4 v = fj[tid + 256 * it];
            d  += dot4(u, v);
            a2 += dot4(u, u);
            b2 += dot4(v, v);
        }
        d  = wave_reduce(d);
        a2 = wave_reduce(a2);
        b2 = wave_reduce(b2);
        if ((tid & 63) == 0) { pr[0][tid >> 6] = d; pr[1][tid >> 6] = a2; pr[2][tid >> 6] = b2; }
        __syncthreads();
        if (tid == 0) {
            const float dd = pr[0][0] + pr[0][1] + pr[0][2] + pr[0][3];
            const float ia = pr[1][0] + pr[1][1] + pr[1][2] + pr[1][3];
            const float jb = pr[2][0] + pr[2][1] + pr[2][2] + pr[2][3];
            ws[WS_L0 + i] = dd / (fmaxf(sqrtf(ia), EPSV) * fmaxf(sqrtf(jb), EPSV)) * INVT;
        }
    }
}

// ---------------------------------------------------------------------------
// fin: ONE block, 256 threads. 4 threads per anchor sum the 16 esum partials
// (float4 loads), lane0-of-4 adds exp(l0) and takes the log (no max needed:
// all logits bounded by |10|), then one wave reduces the 64 per-anchor terms
// and writes out[0] directly (no atomic, no zero-init).
// ---------------------------------------------------------------------------
__global__ __launch_bounds__(256) void ntx_fin(const float* __restrict__ ws,
                                               float* __restrict__ out) {
    const int tid = threadIdx.x;
    const int i = tid >> 2, p = tid & 3;
    float4 v4 = *(const float4*)(ws + WS_ESUM + i * 16 + p * 4);
    float v = v4.x + v4.y + v4.z + v4.w;
    v += __shfl_xor(v, 1);
    v += __shfl_xor(v, 2);
    __shared__ float terms[64];
    if ((tid & 3) == 0) {
        const float l0 = ws[WS_L0 + i];
        terms[i] = -l0 + __logf(v + __expf(l0));
    }
    __syncthreads();
    if (tid < 64) {
        float t = terms[tid];
        t = wave_reduce(t);
        if (tid == 0) out[0] = t * (1.0f / (2.0f * BB));
    }
}

// ---------------------------------------------------------------------------
extern "C" void kernel_launch(void* const* d_in, const int* in_sizes, int n_in,
                              void* d_out, int out_size, void* d_ws, size_t ws_size,
                              hipStream_t stream) {
    const float* ci  = (const float*)d_in[0];
    const float* cj  = (const float*)d_in[1];
    const int*  pids = (const int*) d_in[2];
    const int*  nj   = (const int*) d_in[3];
    const int*  nk   = (const int*) d_in[4];
    float* ws  = (float*)d_ws;
    float* out = (float*)d_out;

    ntx_main<<<1088, 256, 0, stream>>>(ci, cj, pids, nj, nk, ws);
    ntx_fin<<<1, 256, 0, stream>>>(ws, out);
}

// Round 12
// 76.644 us; speedup vs baseline: 1.2502x; 1.2502x over previous
//
#include <hip/hip_runtime.h>
#include <math.h>

#define BB 64          // batch
#define CC 16          // children per sample
#define DD 512         // feature dim
#define LL 8192        // CC*DD flattened length
#define EPSV 1e-8f
#define INVT 10.0f     // 1/TEMPERATURE

// ws layout (floats):
//  [0,1024)    esum : per-(anchor, jt) partial sum of exp(logit) over the
//                     4 j's x 2 sides handled by sim block (i,jt)
//  [1024,1088) l0   : positive logit per anchor (already /T)
#define WS_ESUM 0
#define WS_L0   1024

__device__ __forceinline__ float dot4(float4 a, float4 b) {
    return a.x * b.x + a.y * b.y + a.z * b.z + a.w * b.w;
}

__device__ __forceinline__ float wave_reduce(float v) {
    #pragma unroll
    for (int off = 32; off; off >>= 1) v += __shfl_down(v, off);
    return v;
}

// ---------------------------------------------------------------------------
// main — the session-best structure (r7, 76.6us), restored verbatim.
// Ledger of falsified alternatives (do not retry):
//   - flat it*jj loop for in-wave ILP: r2 (+11us, readfirstlane vmcnt poison),
//     r3 (+35us, launch_bounds(256,4) -> VGPR 64 -> fiv spill, 114MB scratch),
//     r11 (+19us, launch_bounds(256,2) -> 2 blocks/CU co-residency cap).
//   - occupancy: r4 2x blocks (+1us), r10 (256,2) on this source (neutral).
//   - LDS staging to cut gather traffic 45%: r5 (+5us).
//   - bf16 hi/lo MFMA Gram-matrix substitution: r6 (+12us).
//   - grid quantization 1024 blocks: r9 (+1.5us).
//   - single-kernel fusion w/ device fences: r8 (+20us, cross-XCD L2 tax).
// Structure:
//   blocks [0,1024): sim role (jt=b&15, i=b>>4, 4 j's per block; per-jj
//     phase: 16 gathered loads -> interleaved wave_reduces). Row norms and
//     anchor norm accumulate as dot4(v,v) on register-resident data;
//     epilogue finishes logits to exp() locally (|logit|<=10 -> no max pass)
//     and writes ONE esum partial per block.
//   blocks [1024,1088): pos role, anchor i=b-1024: l0 = cos(fi,fj)/T.
// ---------------------------------------------------------------------------
__global__ __launch_bounds__(256) void ntx_main(const float* __restrict__ ci,
                                                const float* __restrict__ cj,
                                                const int* __restrict__ pids,
                                                const int* __restrict__ nj,
                                                const int* __restrict__ nk,
                                                float* __restrict__ ws) {
    const int b = blockIdx.x, tid = threadIdx.x;

    if (b < 1024) {
        // ---- sim role ----
        __shared__ int   sidx[2][4][16];     // [side][jj][c]
        __shared__ float red[4][4][4];       // [jj][{aj,ak,gj,gk}][wave]
        __shared__ float nred[4];            // anchor-norm partials per wave
        const int jt = b & 15;    // 0..15
        const int i  = b >> 4;    // 0..63

        if (tid < 64)        ((int*)sidx)[tid] = nj[i * 1024 + jt * 64 + tid];
        else if (tid < 128)  ((int*)sidx)[tid] = nk[i * 1024 + jt * 64 + (tid - 64)];

        const float4* fi4 = (const float4*)(ci + i * LL);
        float4 fiv[8];
        float nacc = 0.f;
        #pragma unroll
        for (int it = 0; it < 8; ++it) {
            fiv[it] = fi4[tid + 256 * it];
            nacc += dot4(fiv[it], fiv[it]);
        }

        __syncthreads();

        const int d4   = tid & 127;   // float4 offset within a child row
        const int half = tid >> 7;    // c parity handled by this half
        const int wave = tid >> 6;
        const float4* cj4 = (const float4*)cj;
        const float4* ci4 = (const float4*)ci;

        {
            float nr = wave_reduce(nacc);
            if ((tid & 63) == 0) nred[wave] = nr;
        }

        #pragma unroll
        for (int jj = 0; jj < 4; ++jj) {
            const int j = jt * 4 + jj;
            const float4* bj = cj4 + j * CC * 128;
            const float4* bk = ci4 + j * CC * 128;
            float aj = 0.f, ak = 0.f, gj = 0.f, gk = 0.f;
            #pragma unroll
            for (int it = 0; it < 8; ++it) {
                const int c = half + 2 * it;           // (tid + it*256) >> 7
                float4 vj = bj[sidx[0][jj][c] * 128 + d4];
                float4 vk = bk[sidx[1][jj][c] * 128 + d4];
                aj += dot4(fiv[it], vj);
                gj += dot4(vj, vj);
                ak += dot4(fiv[it], vk);
                gk += dot4(vk, vk);
            }
            aj = wave_reduce(aj);
            ak = wave_reduce(ak);
            gj = wave_reduce(gj);
            gk = wave_reduce(gk);
            if ((tid & 63) == 0) {
                red[jj][0][wave] = aj; red[jj][1][wave] = ak;
                red[jj][2][wave] = gj; red[jj][3][wave] = gk;
            }
        }
        __syncthreads();
        if (tid < 4) {
            const int jj = tid, j = jt * 4 + jj;
            const float aj = red[jj][0][0] + red[jj][0][1] + red[jj][0][2] + red[jj][0][3];
            const float ak = red[jj][1][0] + red[jj][1][1] + red[jj][1][2] + red[jj][1][3];
            const float gj = red[jj][2][0] + red[jj][2][1] + red[jj][2][2] + red[jj][2][3];
            const float gk = red[jj][3][0] + red[jj][3][1] + red[jj][3][2] + red[jj][3][3];
            const float si = nred[0] + nred[1] + nred[2] + nred[3];
            const float ni = fmaxf(sqrtf(si), EPSV);
            float e = 0.f;
            if ((j != i) && (pids[j] != pids[i])) {
                const float inv = INVT / ni;
                const float lj = aj / fmaxf(sqrtf(gj), EPSV) * inv;   // in [-10,10]
                const float lk = ak / fmaxf(sqrtf(gk), EPSV) * inv;
                e = __expf(lj) + __expf(lk);                          // <= 4.5e4, safe
            }
            e += __shfl_xor(e, 1);
            e += __shfl_xor(e, 2);
            if (jj == 0) ws[WS_ESUM + i * 16 + jt] = e;
        }
    } else {
        // ---- pos role ----
        __shared__ float pr[3][4];
        const int i = b - 1024;
        const float4* fi = (const float4*)(ci + i * LL);
        const float4* fj = (const float4*)(cj + i * LL);
        float d = 0.f, a2 = 0.f, b2 = 0.f;
        #pragma unroll
        for (int it = 0; it < 8; ++it) {
            float4 u = fi[tid + 256 * it];
            float4 v = fj[tid + 256 * it];
            d  += dot4(u, v);
            a2 += dot4(u, u);
            b2 += dot4(v, v);
        }
        d  = wave_reduce(d);
        a2 = wave_reduce(a2);
        b2 = wave_reduce(b2);
        if ((tid & 63) == 0) { pr[0][tid >> 6] = d; pr[1][tid >> 6] = a2; pr[2][tid >> 6] = b2; }
        __syncthreads();
        if (tid == 0) {
            const float dd = pr[0][0] + pr[0][1] + pr[0][2] + pr[0][3];
            const float ia = pr[1][0] + pr[1][1] + pr[1][2] + pr[1][3];
            const float jb = pr[2][0] + pr[2][1] + pr[2][2] + pr[2][3];
            ws[WS_L0 + i] = dd / (fmaxf(sqrtf(ia), EPSV) * fmaxf(sqrtf(jb), EPSV)) * INVT;
        }
    }
}

// ---------------------------------------------------------------------------
// fin: ONE block, 256 threads. 4 threads per anchor sum the 16 esum partials
// (float4 loads), lane0-of-4 adds exp(l0) and takes the log (no max needed:
// all logits bounded by |10|), then one wave reduces the 64 per-anchor terms
// and writes out[0] directly (no atomic, no zero-init).
// ---------------------------------------------------------------------------
__global__ __launch_bounds__(256) void ntx_fin(const float* __restrict__ ws,
                                               float* __restrict__ out) {
    const int tid = threadIdx.x;
    const int i = tid >> 2, p = tid & 3;
    float4 v4 = *(const float4*)(ws + WS_ESUM + i * 16 + p * 4);
    float v = v4.x + v4.y + v4.z + v4.w;
    v += __shfl_xor(v, 1);
    v += __shfl_xor(v, 2);
    __shared__ float terms[64];
    if ((tid & 3) == 0) {
        const float l0 = ws[WS_L0 + i];
        terms[i] = -l0 + __logf(v + __expf(l0));
    }
    __syncthreads();
    if (tid < 64) {
        float t = terms[tid];
        t = wave_reduce(t);
        if (tid == 0) out[0] = t * (1.0f / (2.0f * BB));
    }
}

// ---------------------------------------------------------------------------
extern "C" void kernel_launch(void* const* d_in, const int* in_sizes, int n_in,
                              void* d_out, int out_size, void* d_ws, size_t ws_size,
                              hipStream_t stream) {
    const float* ci  = (const float*)d_in[0];
    const float* cj  = (const float*)d_in[1];
    const int*  pids = (const int*) d_in[2];
    const int*  nj   = (const int*) d_in[3];
    const int*  nk   = (const int*) d_in[4];
    float* ws  = (float*)d_ws;
    float* out = (float*)d_out;

    ntx_main<<<1088, 256, 0, stream>>>(ci, cj, pids, nj, nk, ws);
    ntx_fin<<<1, 256, 0, stream>>>(ws, out);
}